// Round 1
// 223.195 us; speedup vs baseline: 1.2126x; 1.2126x over previous
//
#include <hip/hip_runtime.h>

#define T_STEPS 256
#define HID 40
#define EPB 16
#define NTHR 1024
#define R0 72            // L0 row stride (shorts): [h0(40) | x(16) | pad]
#define R1 104           // L1 row stride (shorts): [h1(40) | h0(40) | pad]
#define P0 (16 * R0)     // L0 parity stride = 1152 shorts
#define P1 (16 * R1)     // L1 parity stride = 1664 shorts
#define OL1 (2 * P0)     // L1 region offset = 2304 shorts
#define STOT (2 * P0 + 2 * P1)   // 5632 shorts = 11264 B

typedef __attribute__((ext_vector_type(8))) short bf16x8;
typedef __attribute__((ext_vector_type(4))) float f32x4;

__device__ __forceinline__ unsigned short bf16_rne(float v) {
    unsigned int x = __float_as_uint(v);
    unsigned int r = x + 0x7FFFu + ((x >> 16) & 1u);
    return (unsigned short)(r >> 16);
}
// single-instruction bf16 convert (RNE), replaces the 5-op bit-twiddle in the hot loop
__device__ __forceinline__ unsigned short bf16_cvt(float v) {
    unsigned int r;
    asm("v_cvt_pk_bf16_f32 %0, %1, %2" : "=v"(r) : "v"(v), "v"(v));
    return (unsigned short)r;
}
// fast gates: v_exp_f32 computes 2^x; v_rcp_f32 replaces the IEEE divide sequence
// (div_scale/div_fmas/div_fixup ~9 VALU ops + ~30cy chain each). bf16 state makes
// the ~1ulp rcp/exp error irrelevant.
__device__ __forceinline__ float sigm(float v) {
    return __builtin_amdgcn_rcpf(1.0f + __builtin_amdgcn_exp2f(-1.4426950408889634f * v));
}
__device__ __forceinline__ float tanh_f(float v) {
    return 1.0f - 2.0f * __builtin_amdgcn_rcpf(__builtin_amdgcn_exp2f(2.8853900817779268f * v) + 1.0f);
}

#define MF(A_, B_, C_) C_ = __builtin_amdgcn_mfma_f32_16x16x32_bf16(A_, B_, C_, 0, 0, 0)
#define PINV(v) asm volatile("" : "+v"(v))

// r15: 1-TERM bf16 state (no lo compensation; r7-r14's absmax was pinned at
// 2^-9 independent of split order -> the split wasn't the floor) over UNIFIED
// K-concat rows [h_self | input]. r/z slots fuse W_hr*h + W_ir*x in one chain.
// A-frag element at k' = 32c + 8qrow + j: k'<40 -> Whh[rh][k'] (slots r,z,nh);
// 40<=k'<40+KX -> Wih[rx][k'-40] (slots r,z,nx); else 0.
__device__ bf16x8 afrag(const float* Whh, const float* Wih, int KX,
                        int rh, int rx, int c, int qrow) {
    bf16x8 f;
    #pragma unroll
    for (int j = 0; j < 8; ++j) f[j] = 0;
    #pragma unroll
    for (int j = 0; j < 8; ++j) {
        const int k = 32 * c + qrow * 8 + j;
        if (k < 40) {
            if (rh >= 0) f[j] = (short)bf16_rne(Whh[rh * 40 + k]);
        } else if (k < 40 + KX) {
            if (rx >= 0) f[j] = (short)bf16_rne(Wih[rx * KX + (k - 40)]);
        }
    }
    return f;
}

// Structure from r13/r14 (proven): 16 waves, waves 0-5 L0 (tiles 2,2,2,2,1,1),
// waves 6-15 L1 (1 tile); ping-pong parities, 2-step unroll (compile-time
// offsets), bias f32x4 as first MFMA's C operand, 1 barrier/step, layer skew
// (step t: L0 computes h0[t], L1 computes h1[t-1]).
__global__ __launch_bounds__(NTHR, 4)
void gru2_kernel(const float* __restrict__ x,
                 const float* __restrict__ Wih0, const float* __restrict__ Whh0,
                 const float* __restrict__ bih0, const float* __restrict__ bhh0,
                 const float* __restrict__ Wih1, const float* __restrict__ Whh1,
                 const float* __restrict__ bih1, const float* __restrict__ bhh1,
                 float* __restrict__ out)
{
    __shared__ __align__(16) unsigned short S[STOT];

    const int tid  = threadIdx.x;
    const int wid  = tid >> 6;     // 0..15
    const int l    = tid & 63;
    const int col  = l & 15;       // elem (B n, C col)
    const int qrow = l >> 4;
    const int pm   = l & 15;       // A-frag position row
    const int ps   = pm & 3;       // slot (0=r,1=z,2=nx,3=nh)
    const int pu   = pm >> 2;      // unit-in-tile
    const int e0   = blockIdx.x * EPB;

    const bool isL1 = wid >= 6;
    const int  NT   = (!isL1 && wid < 4) ? 2 : 1;
    const int  TA   = isL1 ? (wid - 6) : (wid < 4 ? 2 * wid : wid + 4);
    const int  TB   = (NT == 2) ? TA + 1 : TA;
    const bool dB   = (NT != 2);

    const float* Whh = isL1 ? Whh1 : Whh0;
    const float* Wih = isL1 ? Wih1 : Wih0;
    const float* bih = isL1 ? bih1 : bih0;
    const float* bhh = isL1 ? bhh1 : bhh0;
    const int KX = isL1 ? 40 : 16;

    const int uA = 4 * TA + pu;
    const int rhA = (ps == 2) ? -1 : (ps == 0 ? uA : ps == 1 ? 40 + uA : 80 + uA);
    const int rxA = (ps == 3) ? -1 : (ps == 0 ? uA : ps == 1 ? 40 + uA : 80 + uA);
    const int uB = 4 * TB + pu;
    const int rhB = (dB || ps == 2) ? -1 : (ps == 0 ? uB : ps == 1 ? 40 + uB : 80 + uB);
    const int rxB = (dB || ps == 3) ? -1 : (ps == 0 ? uB : ps == 1 ? 40 + uB : 80 + uB);

    // ---- weight A-frags (4 unified names) + bias vectors, pinned ----
    // L0: F0,F1 = tile A chunks 0,1 ; F2,F3 = tile B chunks 0,1  (K'=56)
    // L1: F0,F1,F2 = tile A chunks 0,1,2 ; F3 dead                (K'=80)
    bf16x8 F0, F1, F2, F3;
    if (!isL1) {
        F0 = afrag(Whh, Wih, KX, rhA, rxA, 0, qrow);
        F1 = afrag(Whh, Wih, KX, rhA, rxA, 1, qrow);
        F2 = afrag(Whh, Wih, KX, rhB, rxB, 0, qrow);
        F3 = afrag(Whh, Wih, KX, rhB, rxB, 1, qrow);
    } else {
        F0 = afrag(Whh, Wih, KX, rhA, rxA, 0, qrow);
        F1 = afrag(Whh, Wih, KX, rhA, rxA, 1, qrow);
        F2 = afrag(Whh, Wih, KX, rhA, rxA, 2, qrow);
        F3 = afrag(Whh, Wih, KX, -1, -1, 0, qrow);
    }
    const int ucA = 4 * TA + qrow;
    const int ucB = 4 * TB + qrow;
    f32x4 BBA, BBB;
    BBA[0] = bih[ucA] + bhh[ucA];
    BBA[1] = bih[40 + ucA] + bhh[40 + ucA];
    BBA[2] = bih[80 + ucA];
    BBA[3] = bhh[80 + ucA];
    BBB[0] = dB ? 0.f : (bih[ucB] + bhh[ucB]);
    BBB[1] = dB ? 0.f : (bih[40 + ucB] + bhh[40 + ucB]);
    BBB[2] = dB ? 0.f : bih[80 + ucB];
    BBB[3] = dB ? 0.f : bhh[80 + ucB];

    PINV(F0); PINV(F1); PINV(F2); PINV(F3);
    PINV(BBA); PINV(BBB);

    // LDS base offsets (shorts); parity added as compile-time immediate in BODY
    const int rdl = isL1 ? (OL1 + col * R1 + qrow * 8) : (col * R0 + qrow * 8);
    const int w0b = col * R0;            // L0 self-row base
    const int w1b = OL1 + col * R1;      // L1 row base
    unsigned short* Sb = &S[0];
    float hA_ = 0.f, hB_ = 0.f;

    // L0 task: write h0' into BOTH rows (self + L1's input span at +40)
#define GATE_L0(C, U, H, WP_) { \
    const float r_ = sigm(C[0]); \
    const float z_ = sigm(C[1]); \
    const float n_ = tanh_f(C[2] + r_ * C[3]); \
    H = n_ + z_ * (H - n_); \
    const unsigned short hb_ = bf16_cvt(H); \
    Sb[w0b + (WP_) * P0 + (U)] = hb_; \
    Sb[w1b + (WP_) * P1 + 40 + (U)] = hb_; }
#define GATE_L1(C, U, H, WP_) { \
    const float r_ = sigm(C[0]); \
    const float z_ = sigm(C[1]); \
    const float n_ = tanh_f(C[2] + r_ * C[3]); \
    H = n_ + z_ * (H - n_); \
    Sb[w1b + (WP_) * P1 + (U)] = bf16_cvt(H); }

    // ---- init: zero all of S (pads must stay 0), stage x[0], preload x[1] ----
    for (int idx = tid; idx < STOT; idx += NTHR) Sb[idx] = 0;
    __syncthreads();
    const bool xth = tid < 256;
    const int xe = tid >> 4, xk = tid & 15;
    const float* xrow = x + (size_t)(e0 + xe) * (T_STEPS * 16) + xk;
    float xold = 0.f;
    if (xth) {
        Sb[xe * R0 + 40 + xk] = bf16_cvt(xrow[0]);
        xold = xrow[16];
    }
    __syncthreads();

#define BODY(RP) { \
    float xnew = 0.f; \
    if (xth && t + 2 < T_STEPS) xnew = xrow[(t + 2) * 16]; \
    if (!isL1) { \
        const bf16x8 S0 = *(const bf16x8*)(Sb + rdl + (RP) * P0); \
        const bf16x8 S1 = *(const bf16x8*)(Sb + rdl + (RP) * P0 + 32); \
        if (t < T_STEPS) { \
            f32x4 c = __builtin_amdgcn_mfma_f32_16x16x32_bf16(F0, S0, BBA, 0, 0, 0); \
            MF(F1, S1, c); \
            GATE_L0(c, ucA, hA_, (1 - (RP))); \
            if (NT == 2) { \
                f32x4 d = __builtin_amdgcn_mfma_f32_16x16x32_bf16(F2, S0, BBB, 0, 0, 0); \
                MF(F3, S1, d); \
                GATE_L0(d, ucB, hB_, (1 - (RP))); \
            } \
        } \
    } else { \
        const bf16x8 S0 = *(const bf16x8*)(Sb + rdl + (RP) * P1); \
        const bf16x8 S1 = *(const bf16x8*)(Sb + rdl + (RP) * P1 + 32); \
        const bf16x8 S2 = *(const bf16x8*)(Sb + rdl + (RP) * P1 + 64); \
        f32x4 c = __builtin_amdgcn_mfma_f32_16x16x32_bf16(F0, S0, BBA, 0, 0, 0); \
        MF(F1, S1, c); MF(F2, S2, c); \
        if (t > 0) GATE_L1(c, ucA, hA_, (1 - (RP))); \
    } \
    if (xth && t < T_STEPS - 1) { \
        Sb[xe * R0 + (1 - (RP)) * P0 + 40 + xk] = bf16_cvt(xold); \
    } \
    xold = xnew; \
    ++t; \
    __syncthreads(); }

    int t = 0;
    #pragma unroll 1
    for (int it = 0; it < 128; ++it) {
        BODY(0)
        BODY(1)
    }
    BODY(0)   // t = 256: L1 finishes h1[255]; L0 inactive

    // ---- h1[255] straight from registers (10 L1 waves x 4 units = 40) ----
    if (isL1) {
        out[(size_t)(e0 + col) * HID + ucA] = hA_;
    }
}

extern "C" void kernel_launch(void* const* d_in, const int* in_sizes, int n_in,
                              void* d_out, int out_size, void* d_ws, size_t ws_size,
                              hipStream_t stream) {
    const float* x    = (const float*)d_in[0];
    const float* Wih0 = (const float*)d_in[1];
    const float* Whh0 = (const float*)d_in[2];
    const float* bih0 = (const float*)d_in[3];
    const float* bhh0 = (const float*)d_in[4];
    const float* Wih1 = (const float*)d_in[5];
    const float* Whh1 = (const float*)d_in[6];
    const float* bih1 = (const float*)d_in[7];
    const float* bhh1 = (const float*)d_in[8];
    float* out = (float*)d_out;

    dim3 grid(4096 / EPB), block(NTHR);
    hipLaunchKernelGGL(gru2_kernel, grid, block, 0, stream,
                       x, Wih0, Whh0, bih0, bhh0, Wih1, Whh1, bih1, bhh1, out);
}